// Round 7
// baseline (477.017 us; speedup 1.0000x reference)
//
#include <hip/hip_runtime.h>
#include <hip/hip_bf16.h>
#include <stdint.h>

// R7 (466.7us) unfused baseline. R8/R10/R11 (~500us) fused-LN 1-block/CU
//   geometries all fail -> keep 2-blocks/CU gemm.
// R12 (462.1us): gemm2 -> partial stats (S,Q,U), no Y write, finalize2.
// R13 (450.2us): fused_prep (pad+w+scan+k12 in 1 dispatch), dead-row skips
//   in ln/prep, dead-block exit in gemms, gather+finalize merged.
// R14: OVERLAP gather with gemm1 in one dispatch.  gather depends only on
//   scan; it is pure-BW (256MB out write is roofline-mandatory ~54us) while
//   gemm1 is compute/L2-bound.  Grid = [32768 gather blocks | 512 gemm
//   blocks]: short gather blocks stream through CU slots under gemm1's
//   ~60us shadow.  Combined BW (~410MB / 6.3TB/s ~ 65us) ~ gemm1 duration
//   -> gather nearly free.  finalize2 back to its own tiny dispatch.

typedef _Float16 f16;
typedef _Float16 f16x8 __attribute__((ext_vector_type(8)));
typedef float f32x4 __attribute__((ext_vector_type(4)));

#define B_    32
#define T_    1024
#define TP_   1026
#define C_    512
#define LMAX_ 4096
#define KDIM  1536

// workspace byte offsets (all 256-aligned)
#define XPAD_OFF   0u
#define H1PAD_OFF  33619968u     // 32*1026*512*2
#define W1T_OFF    67239936u
#define W2T_OFF    68812800u
#define YWS_OFF    70385664u     // f16, 32 MB
#define TOT_OFF    137494528u
#define IDX_OFF    137495040u    // + 32*4096*4 = ends 138019328
#define GWL_OFF    138019328u    // 512 f32
#define K12_OFF    138021376u    // 2 f32 (256-pad)
#define STAT2_OFF  138021888u    // 32768*2 float4 = 1 MB

#define AS1C(p) ((const __attribute__((address_space(1))) void*)(p))
#define AS3(p)  ((__attribute__((address_space(3))) void*)(p))

// fused_prep grid partition (1024 threads/block)
#define PP_BLOCKS   2052         // prep_pad: 32832 rows / 16 per block
#define PW_BLOCKS   256          // prep_w: 1024 units / 4 per block
#define SCAN_BLOCKS 32

// g1_gather grid partition (256 threads/block)
#define GATHER_BLOCKS 32768      // B_*LMAX_/4 rows, wave per row
#define G1_BLOCKS     512        // gemm1: 256 m-blocks x 2 n-panels

// ---------------------------------------------------------------------------
// One dispatch running four independent prep stages concurrently.
__global__ __launch_bounds__(1024) void fused_prep(
        const float* __restrict__ batch, f16* __restrict__ xpad,
        f16* __restrict__ h1pad, const int* __restrict__ tlen,
        const float* __restrict__ w1, const float* __restrict__ w2,
        f16* __restrict__ w1t, f16* __restrict__ w2t,
        const float* __restrict__ g2, const float* __restrict__ be2,
        const float* __restrict__ lw, float* __restrict__ gwl,
        float* __restrict__ k12,
        const int* __restrict__ dur, int* __restrict__ idxarr,
        int* __restrict__ total, float* __restrict__ mel_out) {
    __shared__ int sd[1024];
    __shared__ int sv[1024];
    __shared__ float rk[8][2];
    const int bid = blockIdx.x;
    const int tid = threadIdx.x;

    if (bid < PP_BLOCKS) {                       // ---- prep_pad ----
        int row = bid * 16 + (tid >> 6);         // 0 .. 32831
        int lane = tid & 63;
        int b = row / TP_, tt = row % TP_;
        size_t dsto = (size_t)row * C_ + lane * 8;
        if (tt == 0 || tt == TP_ - 1) {
            f16x8 z = {};
            *(f16x8*)(xpad + dsto) = z;
            *(f16x8*)(h1pad + dsto) = z;
        } else if (tt <= tlen[b] + 130) {        // dead rows stay poisoned
            const float* src = batch + ((size_t)(b * T_ + tt - 1)) * C_ + lane * 8;
            float4 v0 = ((const float4*)src)[0];
            float4 v1 = ((const float4*)src)[1];
            f16x8 h;
            h[0] = (f16)v0.x; h[1] = (f16)v0.y; h[2] = (f16)v0.z; h[3] = (f16)v0.w;
            h[4] = (f16)v1.x; h[5] = (f16)v1.y; h[6] = (f16)v1.z; h[7] = (f16)v1.w;
            *(f16x8*)(xpad + dsto) = h;
        }
        return;
    }
    if (bid < PP_BLOCKS + PW_BLOCKS) {           // ---- prep_w ----
        int unit = (bid - PP_BLOCKS) * 4 + (tid >> 8);  // 0..1023
        int o = unit & 511;
        const float* w = (unit >> 9) ? w2 : w1;
        f16* wt = (unit >> 9) ? w2t : w1t;
        int tl = tid & 255;
        for (int j = tl; j < KDIM; j += 256) {
            int tap = j >> 9, i = j & 511;
            wt[(size_t)o * KDIM + j] = (f16)w[(size_t)o * KDIM + i * 3 + tap];
        }
        return;
    }
    if (bid < PP_BLOCKS + PW_BLOCKS + SCAN_BLOCKS) {   // ---- scan ----
        int b = bid - (PP_BLOCKS + PW_BLOCKS);
        int t = tid;
        int L = tlen[b];
        int valid = (t < L) ? 1 : 0;
        int d = valid ? dur[b * T_ + t] : 0;
        sd[t] = d; sv[t] = valid;
        __syncthreads();
        for (int off = 1; off < 1024; off <<= 1) {
            int x = 0, y = 0;
            if (t >= off) { x = sd[t - off]; y = sv[t - off]; }
            __syncthreads();
            sd[t] += x; sv[t] += y;
            __syncthreads();
        }
        int totd = sd[1023];
        int cur  = (totd == 0) ? sv[t] : sd[t];
        int prev = (t == 0) ? 0 : ((totd == 0) ? sv[t - 1] : sd[t - 1]);
        for (int f = prev; f < cur; f++) idxarr[b * LMAX_ + f] = t;
        if (t == 1023) {
            int tt = (totd == 0) ? sv[1023] : totd;
            total[b] = tt;
            mel_out[b] = (float)tt;
        }
        return;
    }
    // ---- gwl + K1/K2 (single block) ----
    {
        float k1 = 0.f, k2 = 0.f;
        if (tid < C_) {
            float gw_ = g2[tid] * lw[tid];
            gwl[tid] = gw_;
            k1 = gw_;
            k2 = be2[tid] * lw[tid];
        }
#pragma unroll
        for (int m = 32; m; m >>= 1) {
            k1 += __shfl_xor(k1, m, 64);
            k2 += __shfl_xor(k2, m, 64);
        }
        int wv = tid >> 6;
        if ((tid & 63) == 0 && wv < 8) { rk[wv][0] = k1; rk[wv][1] = k2; }
        __syncthreads();
        if (tid == 0) {
            float a1 = 0.f, a2 = 0.f;
#pragma unroll
            for (int i = 0; i < 8; i++) { a1 += rk[i][0]; a2 += rk[i][1]; }
            k12[0] = a1; k12[1] = a2;
        }
    }
}

// ---------------------------------------------------------------------------
// Merged dispatch: [0, 32768) regulate-gather rows; [32768, 33280) gemm1.
// Gather (pure HBM BW) streams through CU slots while the 512 long-running
// gemm1 blocks compute -> its ~340MB of traffic hides under gemm1's shadow.
// gemm1: implicit-GEMM conv (R7-verified): BM=128 x BN=256, 4 waves, wave
// tile 64x128, BK=64, 48KB LDS -> 2 blocks/CU.  XOR granule swizzle.
// Y = relu(A@Bw^T + bias), f16.  Dead blocks (t0 > tlen[b]) exit early.
__global__ __launch_bounds__(256, 2) void g1_gather(
        const float* __restrict__ batch, const int* __restrict__ idxarr,
        const int* __restrict__ total, float* __restrict__ out,
        const f16* __restrict__ A, const f16* __restrict__ Bw,
        const float* __restrict__ bias, f16* __restrict__ Y,
        const int* __restrict__ tlen) {
    __shared__ f16 As[128 * 64];   // 16 KB
    __shared__ f16 Bs[256 * 64];   // 32 KB

    if (blockIdx.x < GATHER_BLOCKS) {
        // ---------------- gather ----------------
        int gw = blockIdx.x * 4 + (threadIdx.x >> 6);  // 0 .. B_*LMAX_-1
        int lane = threadIdx.x & 63;
        int b = gw >> 12;
        int l = gw & (LMAX_ - 1);
        int tot = total[b];
        float4* dst = (float4*)(out + ((size_t)b * LMAX_ + l) * C_);
        if (l < tot) {
            int idx = idxarr[gw];
            const float4* src = (const float4*)(batch + ((size_t)b * T_ + idx) * C_);
            dst[lane] = src[lane];
            dst[lane + 64] = src[lane + 64];
        } else {
            float4 z = {0.f, 0.f, 0.f, 0.f};
            dst[lane] = z;
            dst[lane + 64] = z;
        }
        return;
    }

    // ---------------- gemm1 ----------------
    const int gb = blockIdx.x - GATHER_BLOCKS;   // 0..511
    const int m0 = (gb & 255) * 128;
    const int n0 = (gb >> 8) * 256;
    {
        const int bb = m0 >> 10, t0 = m0 & 1023;
        if (t0 > tlen[bb]) return;               // block-uniform dead exit
    }
    const int tid = threadIdx.x;
    const int lane = tid & 63;
    const int w = tid >> 6;        // 0..3
    const int arow0 = (m0 >> 10) * TP_ + (m0 & 1023);
    const int wm = (w & 1) * 64;
    const int wn = (w >> 1) * 128;

    f32x4 acc[4][8];
#pragma unroll
    for (int i = 0; i < 4; i++)
#pragma unroll
        for (int j = 0; j < 8; j++) acc[i][j] = (f32x4){0.f, 0.f, 0.f, 0.f};

    const int lrow = lane >> 3;                  // 0..7
    const int gran = (lane & 7) ^ lrow;          // swizzled source granule
    const f16* aB = A + (size_t)(arow0 + lrow) * C_ + gran * 8;
    const f16* bB = Bw + (size_t)(n0 + lrow) * KDIM + gran * 8;

    for (int kk = 0; kk < KDIM; kk += 64) {
        __syncthreads();
#pragma unroll
        for (int i = 0; i < 4; i++) {           // A: 16 wave-loads / 4 waves
            const int rb = (w + i * 4) * 8;
            __builtin_amdgcn_global_load_lds(AS1C(aB + (size_t)rb * C_ + kk),
                                             AS3(&As[rb * 64]), 16, 0, 0);
        }
#pragma unroll
        for (int j = 0; j < 8; j++) {           // B: 32 wave-loads / 4 waves
            const int rb = (w + j * 4) * 8;
            __builtin_amdgcn_global_load_lds(AS1C(bB + (size_t)rb * KDIM + kk),
                                             AS3(&Bs[rb * 64]), 16, 0, 0);
        }
        __syncthreads();   // drains vmcnt -> LDS tiles complete
#pragma unroll
        for (int ks = 0; ks < 2; ks++) {
            const int sl = ((ks << 2) + (lane >> 4)) ^ (lane & 7);
            f16x8 af[4], bf[8];
#pragma unroll
            for (int mi = 0; mi < 4; mi++)
                af[mi] = *(const f16x8*)&As[(wm + mi * 16 + (lane & 15)) * 64 + sl * 8];
#pragma unroll
            for (int ni = 0; ni < 8; ni++)
                bf[ni] = *(const f16x8*)&Bs[(wn + ni * 16 + (lane & 15)) * 64 + sl * 8];
#pragma unroll
            for (int mi = 0; mi < 4; mi++)
#pragma unroll
                for (int ni = 0; ni < 8; ni++)
                    acc[mi][ni] = __builtin_amdgcn_mfma_f32_16x16x32_f16(
                        af[mi], bf[ni], acc[mi][ni], 0, 0, 0);
        }
    }

    const int col = lane & 15;
    const int row4 = (lane >> 4) * 4;
#pragma unroll
    for (int ni = 0; ni < 8; ni++) {
        int n = n0 + wn + ni * 16 + col;
        float bn = bias[n];
#pragma unroll
        for (int mi = 0; mi < 4; mi++) {
#pragma unroll
            for (int r = 0; r < 4; r++) {
                int m = m0 + wm + mi * 16 + row4 + r;
                float v = acc[mi][ni][r] + bn;
                Y[(size_t)m * C_ + n] = (f16)(v > 0.f ? v : 0.f);
            }
        }
    }
}

// ---------------------------------------------------------------------------
// gemm2: same R7 structure; emits per-row partial stats (S,Q,U) over this
// block's 256 cols -> stats[m][nblk]; no Y write.  Dead: t0 >= tlen[b].
__global__ __launch_bounds__(256, 2) void gemm2_k(const f16* __restrict__ A,
                                                  const f16* __restrict__ Bw,
                                                  const float* __restrict__ bias,
                                                  const float* __restrict__ gwl,
                                                  float4* __restrict__ stats,
                                                  const int* __restrict__ tlen) {
    __shared__ f16 As[128 * 64];   // 16 KB
    __shared__ f16 Bs[256 * 64];   // 32 KB
    const int m0 = blockIdx.x * 128;
    {
        const int bb = m0 >> 10, t0 = m0 & 1023;
        if (t0 >= tlen[bb]) return;              // block-uniform dead exit
    }
    const int tid = threadIdx.x;
    const int lane = tid & 63;
    const int w = tid >> 6;        // 0..3
    const int n0 = blockIdx.y * 256;
    const int arow0 = (m0 >> 10) * TP_ + (m0 & 1023);
    const int wm = (w & 1) * 64;
    const int wn = (w >> 1) * 128;

    f32x4 acc[4][8];
#pragma unroll
    for (int i = 0; i < 4; i++)
#pragma unroll
        for (int j = 0; j < 8; j++) acc[i][j] = (f32x4){0.f, 0.f, 0.f, 0.f};

    const int lrow = lane >> 3;                  // 0..7
    const int gran = (lane & 7) ^ lrow;          // swizzled source granule
    const f16* aB = A + (size_t)(arow0 + lrow) * C_ + gran * 8;
    const f16* bB = Bw + (size_t)(n0 + lrow) * KDIM + gran * 8;

    for (int kk = 0; kk < KDIM; kk += 64) {
        __syncthreads();
#pragma unroll
        for (int i = 0; i < 4; i++) {
            const int rb = (w + i * 4) * 8;
            __builtin_amdgcn_global_load_lds(AS1C(aB + (size_t)rb * C_ + kk),
                                             AS3(&As[rb * 64]), 16, 0, 0);
        }
#pragma unroll
        for (int j = 0; j < 8; j++) {
            const int rb = (w + j * 4) * 8;
            __builtin_amdgcn_global_load_lds(AS1C(bB + (size_t)rb * KDIM + kk),
                                             AS3(&Bs[rb * 64]), 16, 0, 0);
        }
        __syncthreads();
#pragma unroll
        for (int ks = 0; ks < 2; ks++) {
            const int sl = ((ks << 2) + (lane >> 4)) ^ (lane & 7);
            f16x8 af[4], bf[8];
#pragma unroll
            for (int mi = 0; mi < 4; mi++)
                af[mi] = *(const f16x8*)&As[(wm + mi * 16 + (lane & 15)) * 64 + sl * 8];
#pragma unroll
            for (int ni = 0; ni < 8; ni++)
                bf[ni] = *(const f16x8*)&Bs[(wn + ni * 16 + (lane & 15)) * 64 + sl * 8];
#pragma unroll
            for (int mi = 0; mi < 4; mi++)
#pragma unroll
                for (int ni = 0; ni < 8; ni++)
                    acc[mi][ni] = __builtin_amdgcn_mfma_f32_16x16x32_f16(
                        af[mi], bf[ni], acc[mi][ni], 0, 0, 0);
        }
    }

    const int col = lane & 15;
    const int row4 = (lane >> 4) * 4;

    float bn[8], gw[8];
#pragma unroll
    for (int ni = 0; ni < 8; ni++) {
        int n = n0 + wn + ni * 16 + col;
        bn[ni] = bias[n];
        gw[ni] = gwl[n];
    }
    float s_[4][4], q_[4][4], u_[4][4];
#pragma unroll
    for (int mi = 0; mi < 4; mi++)
#pragma unroll
        for (int r = 0; r < 4; r++) { s_[mi][r] = 0.f; q_[mi][r] = 0.f; u_[mi][r] = 0.f; }
#pragma unroll
    for (int mi = 0; mi < 4; mi++)
#pragma unroll
        for (int ni = 0; ni < 8; ni++)
#pragma unroll
            for (int r = 0; r < 4; r++) {
                float v = acc[mi][ni][r] + bn[ni];
                v = v > 0.f ? v : 0.f;
                s_[mi][r] += v;
                q_[mi][r] += v * v;
                u_[mi][r] += v * gw[ni];
            }
#pragma unroll
    for (int m = 8; m; m >>= 1)
#pragma unroll
        for (int mi = 0; mi < 4; mi++)
#pragma unroll
            for (int r = 0; r < 4; r++) {
                s_[mi][r] += __shfl_xor(s_[mi][r], m, 64);
                q_[mi][r] += __shfl_xor(q_[mi][r], m, 64);
                u_[mi][r] += __shfl_xor(u_[mi][r], m, 64);
            }
    __syncthreads();                       // main-loop LDS reads done
    float* red = (float*)As;               // [2][128][3] = 3 KB
    if (col == 0) {
#pragma unroll
        for (int mi = 0; mi < 4; mi++)
#pragma unroll
            for (int r = 0; r < 4; r++) {
                int row = wm + mi * 16 + row4 + r;   // 0..127
                int idx = ((w >> 1) * 128 + row) * 3;
                red[idx]     = s_[mi][r];
                red[idx + 1] = q_[mi][r];
                red[idx + 2] = u_[mi][r];
            }
    }
    __syncthreads();
    if (tid < 128) {
        float S = red[tid * 3]     + red[(128 + tid) * 3];
        float Q = red[tid * 3 + 1] + red[(128 + tid) * 3 + 1];
        float U = red[tid * 3 + 2] + red[(128 + tid) * 3 + 2];
        stats[(size_t)(m0 + tid) * 2 + blockIdx.y] = (float4){S, Q, U, 0.f};
    }
}

// ---------------------------------------------------------------------------
// LayerNorm over C=512 (input f16), wave per row, write fp16 into h1pad.
// Skips rows t > tlen[b] (outputs never read by live gemm2 rows).
__global__ __launch_bounds__(256) void ln_kernel(const f16* __restrict__ Y,
                                                 const float* __restrict__ g,
                                                 const float* __restrict__ be,
                                                 f16* __restrict__ hpad,
                                                 const int* __restrict__ tlen) {
    int row = blockIdx.x * 4 + (threadIdx.x >> 6);
    int lane = threadIdx.x & 63;
    int b = row >> 10, t = row & 1023;
    if (t > tlen[b]) return;                 // wave-uniform
    f16x8 yv = *(const f16x8*)(Y + (size_t)row * C_ + lane * 8);
    float v[8];
#pragma unroll
    for (int i = 0; i < 8; i++) v[i] = (float)yv[i];
    float s = 0.f, q = 0.f;
#pragma unroll
    for (int i = 0; i < 8; i++) { s += v[i]; q += v[i] * v[i]; }
#pragma unroll
    for (int m = 32; m; m >>= 1) { s += __shfl_xor(s, m, 64); q += __shfl_xor(q, m, 64); }
    float mu = s * (1.f / 512.f);
    float x = q * (1.f / 512.f) - mu * mu + 1e-5f;
    float rs = rsqrtf(x);
    rs = rs * (1.5f - 0.5f * x * rs * rs);   // Newton refine
    const float4 g0 = ((const float4*)g)[lane * 2], g1 = ((const float4*)g)[lane * 2 + 1];
    const float4 e0 = ((const float4*)be)[lane * 2], e1 = ((const float4*)be)[lane * 2 + 1];
    f16x8 h;
    h[0] = (f16)((v[0] - mu) * rs * g0.x + e0.x);
    h[1] = (f16)((v[1] - mu) * rs * g0.y + e0.y);
    h[2] = (f16)((v[2] - mu) * rs * g0.z + e0.z);
    h[3] = (f16)((v[3] - mu) * rs * g0.w + e0.w);
    h[4] = (f16)((v[4] - mu) * rs * g1.x + e1.x);
    h[5] = (f16)((v[5] - mu) * rs * g1.y + e1.y);
    h[6] = (f16)((v[6] - mu) * rs * g1.z + e1.z);
    h[7] = (f16)((v[7] - mu) * rs * g1.w + e1.w);
    *(f16x8*)(hpad + ((size_t)(b * TP_ + t + 1)) * C_ + lane * 8) = h;
}

// ---------------------------------------------------------------------------
// finalize: pred[m] = mask * (rs*(U - mu*K1) + K2 + lb)
__global__ __launch_bounds__(256) void finalize2(const float4* __restrict__ stats,
                                                 const float* __restrict__ k12,
                                                 const float* __restrict__ lb,
                                                 const int* __restrict__ tlen,
                                                 float* __restrict__ pred) {
    int m = blockIdx.x * 256 + threadIdx.x;    // grid 128 -> 32768
    float4 a = stats[(size_t)m * 2];
    float4 b = stats[(size_t)m * 2 + 1];
    float S = a.x + b.x, Q = a.y + b.y, U = a.z + b.z;
    float mu = S * (1.f / 512.f);
    float x = Q * (1.f / 512.f) - mu * mu + 1e-5f;
    float rs = rsqrtf(x);
    rs = rs * (1.5f - 0.5f * x * rs * rs);
    float p = rs * (U - mu * k12[0]) + k12[1] + lb[0];
    int bb = m >> 10, t = m & 1023;
    pred[m] = (t < tlen[bb]) ? p : 0.f;
}

// ---------------------------------------------------------------------------
extern "C" void kernel_launch(void* const* d_in, const int* in_sizes, int n_in,
                              void* d_out, int out_size, void* d_ws, size_t ws_size,
                              hipStream_t stream) {
    const float* batch = (const float*)d_in[0];
    const int* tlen    = (const int*)d_in[1];
    const int* durs    = (const int*)d_in[3];
    const float* w1  = (const float*)d_in[4];
    const float* b1  = (const float*)d_in[5];
    const float* g1  = (const float*)d_in[6];
    const float* be1 = (const float*)d_in[7];
    const float* w2  = (const float*)d_in[8];
    const float* b2  = (const float*)d_in[9];
    const float* g2  = (const float*)d_in[10];
    const float* be2 = (const float*)d_in[11];
    const float* lw  = (const float*)d_in[12];
    const float* lb  = (const float*)d_in[13];

    float* out      = (float*)d_out;
    float* mel_out  = out + (size_t)B_ * LMAX_ * C_;
    float* pred_out = mel_out + B_;

    char* ws    = (char*)d_ws;
    f16* xpad   = (f16*)(ws + XPAD_OFF);
    f16* h1pad  = (f16*)(ws + H1PAD_OFF);
    f16* w1t    = (f16*)(ws + W1T_OFF);
    f16* w2t    = (f16*)(ws + W2T_OFF);
    f16* yws    = (f16*)(ws + YWS_OFF);
    int* tot    = (int*)(ws + TOT_OFF);
    int* idxarr = (int*)(ws + IDX_OFF);
    float* gwl  = (float*)(ws + GWL_OFF);
    float* k12  = (float*)(ws + K12_OFF);
    float4* st2 = (float4*)(ws + STAT2_OFF);

    fused_prep<<<PP_BLOCKS + PW_BLOCKS + SCAN_BLOCKS + 1, 1024, 0, stream>>>(
        batch, xpad, h1pad, tlen, w1, w2, w1t, w2t,
        g2, be2, lw, gwl, k12, durs, idxarr, tot, mel_out);
    g1_gather<<<GATHER_BLOCKS + G1_BLOCKS, 256, 0, stream>>>(
        batch, idxarr, tot, out, xpad, w1t, b1, yws, tlen);
    ln_kernel<<<8192, 256, 0, stream>>>(yws, g1, be1, h1pad, tlen);
    gemm2_k<<<dim3(256, 2), 256, 0, stream>>>(h1pad, w2t, b2, gwl, st2, tlen);
    finalize2<<<128, 256, 0, stream>>>(st2, k12, lb, tlen, pred_out);
}

// Round 8
// 467.297 us; speedup vs baseline: 1.0208x; 1.0208x over previous
//
#include <hip/hip_runtime.h>
#include <hip/hip_bf16.h>
#include <stdint.h>

// R7 466.7 unfused baseline. R8/R10/R11 ~500: 1-block/CU fused geometries fail.
// R12 462.1: gemm2 -> partial stats, no Y write. R13 450.2: fused_prep +
//   dead-work skips (BEST). R14 477.0: gather+gemm1 merge REGRESSED -27us --
//   shared launch_bounds/LDS/VGPR throttled gather to 2 blocks/CU and
//   dispatch order prevented overlap.  Reverted.
// R15: R13 + flatmm-style gemms.  B never touches LDS: prep_w pre-shuffles
//   weights into MFMA fragment order (B2[kt][nt][ks][lane] 16B frags), gemm
//   reads them as coalesced 1KB global loads from L2 (B2=1.5MB, L2-resident).
//   Wave tile 128Mx64N -> each B col read by ONE wave (B L2 traffic 393MB,
//   ~16B/cyc/CU << 56 ceiling).  LDS holds only A (16KB): staging 12->4
//   loads/wave-iter (3x shorter barrier drain), LDS reads 24->16/wave-iter.
//   MFMA floor 24.8us/gemm; predict ~35-40us each (was 50-55).

typedef _Float16 f16;
typedef _Float16 f16x8 __attribute__((ext_vector_type(8)));
typedef float f32x4 __attribute__((ext_vector_type(4)));

#define B_    32
#define T_    1024
#define TP_   1026
#define C_    512
#define LMAX_ 4096
#define KDIM  1536
#define NKT   24         // KDIM/64

// workspace byte offsets (all 256-aligned)
#define XPAD_OFF   0u
#define H1PAD_OFF  33619968u     // 32*1026*512*2
#define W1T_OFF    67239936u     // 1.5MB fragment-ordered B2 for layer 1
#define W2T_OFF    68812800u     // 1.5MB fragment-ordered B2 for layer 2
#define YWS_OFF    70385664u     // f16, 32 MB
#define TOT_OFF    137494528u
#define IDX_OFF    137495040u    // + 32*4096*4 = ends 138019328
#define GWL_OFF    138019328u    // 512 f32
#define K12_OFF    138021376u    // 2 f32 (256-pad)
#define STAT2_OFF  138021888u    // 32768*2 float4 = 1 MB

#define AS1C(p) ((const __attribute__((address_space(1))) void*)(p))
#define AS3(p)  ((__attribute__((address_space(3))) void*)(p))

// fused_prep grid partition (1024 threads/block)
#define PP_BLOCKS   2052         // prep_pad: 32832 rows / 16 per block
#define PW_BLOCKS   256          // B2 shuffle: 2*98304 frags / 1024 per block
#define SCAN_BLOCKS 32
#define FRAGS_PER_M 98304        // 24*32*2*64

// ---------------------------------------------------------------------------
// One dispatch running four independent prep stages concurrently:
//   [0,2052)      prep_pad  (16 rows/block, wave per row, dead-row skip)
//   [2052,2308)   B2 fragment shuffle for w1,w2 (1 frag = 8 f16 per thread)
//   [2308,2340)   scan (1 batch/block)
//   [2340]        gwl + K1/K2
__global__ __launch_bounds__(1024) void fused_prep(
        const float* __restrict__ batch, f16* __restrict__ xpad,
        f16* __restrict__ h1pad, const int* __restrict__ tlen,
        const float* __restrict__ w1, const float* __restrict__ w2,
        f16* __restrict__ w1t, f16* __restrict__ w2t,
        const float* __restrict__ g2, const float* __restrict__ be2,
        const float* __restrict__ lw, float* __restrict__ gwl,
        float* __restrict__ k12,
        const int* __restrict__ dur, int* __restrict__ idxarr,
        int* __restrict__ total, float* __restrict__ mel_out) {
    __shared__ int sd[1024];
    __shared__ int sv[1024];
    __shared__ float rk[8][2];
    const int bid = blockIdx.x;
    const int tid = threadIdx.x;

    if (bid < PP_BLOCKS) {                       // ---- prep_pad ----
        int row = bid * 16 + (tid >> 6);         // 0 .. 32831
        int lane = tid & 63;
        int b = row / TP_, tt = row % TP_;
        size_t dsto = (size_t)row * C_ + lane * 8;
        if (tt == 0 || tt == TP_ - 1) {
            f16x8 z = {};
            *(f16x8*)(xpad + dsto) = z;
            *(f16x8*)(h1pad + dsto) = z;
        } else if (tt <= tlen[b] + 130) {        // dead rows stay poisoned
            const float* src = batch + ((size_t)(b * T_ + tt - 1)) * C_ + lane * 8;
            float4 v0 = ((const float4*)src)[0];
            float4 v1 = ((const float4*)src)[1];
            f16x8 h;
            h[0] = (f16)v0.x; h[1] = (f16)v0.y; h[2] = (f16)v0.z; h[3] = (f16)v0.w;
            h[4] = (f16)v1.x; h[5] = (f16)v1.y; h[6] = (f16)v1.z; h[7] = (f16)v1.w;
            *(f16x8*)(xpad + dsto) = h;
        }
        return;
    }
    if (bid < PP_BLOCKS + PW_BLOCKS) {           // ---- B2 fragment shuffle ----
        // B2 f16 index: (((kt*32+nt)*2+ks)*64 + lane)*8 + j  holds
        //   w[o][i][tap] with o = nt*16+(lane&15),
        //   k = kt*64 + ((ks<<2)+(lane>>4))*8 + j, tap = k>>9, i = k&511.
        // (Derived from the proven LDS-read fragment semantics.)
        int gid = (bid - PP_BLOCKS) * 1024 + tid;        // 0 .. 262143
        if (gid < 2 * FRAGS_PER_M) {
            const float* w = (gid >= FRAGS_PER_M) ? w2 : w1;
            f16* wt = (gid >= FRAGS_PER_M) ? w2t : w1t;
            int fid = (gid >= FRAGS_PER_M) ? gid - FRAGS_PER_M : gid;
            int kt   = fid >> 12;          // /4096
            int rem  = fid & 4095;
            int nt   = rem >> 7;           // /128
            int rem2 = rem & 127;
            int ks   = rem2 >> 6;
            int l    = rem2 & 63;
            int o     = nt * 16 + (l & 15);
            int kbase = kt * 64 + (((ks << 2) + (l >> 4)) << 3);
            int tap   = kbase >> 9;
            int i0    = kbase & 511;
            const float* src = w + (size_t)o * KDIM + (size_t)i0 * 3 + tap;
            f16x8 h;
#pragma unroll
            for (int j = 0; j < 8; j++) h[j] = (f16)src[j * 3];
            *(f16x8*)(wt + (size_t)fid * 8) = h;
        }
        return;
    }
    if (bid < PP_BLOCKS + PW_BLOCKS + SCAN_BLOCKS) {   // ---- scan ----
        int b = bid - (PP_BLOCKS + PW_BLOCKS);
        int t = tid;
        int L = tlen[b];
        int valid = (t < L) ? 1 : 0;
        int d = valid ? dur[b * T_ + t] : 0;
        sd[t] = d; sv[t] = valid;
        __syncthreads();
        for (int off = 1; off < 1024; off <<= 1) {
            int x = 0, y = 0;
            if (t >= off) { x = sd[t - off]; y = sv[t - off]; }
            __syncthreads();
            sd[t] += x; sv[t] += y;
            __syncthreads();
        }
        int totd = sd[1023];
        int cur  = (totd == 0) ? sv[t] : sd[t];
        int prev = (t == 0) ? 0 : ((totd == 0) ? sv[t - 1] : sd[t - 1]);
        for (int f = prev; f < cur; f++) idxarr[b * LMAX_ + f] = t;
        if (t == 1023) {
            int tt = (totd == 0) ? sv[1023] : totd;
            total[b] = tt;
            mel_out[b] = (float)tt;
        }
        return;
    }
    // ---- gwl + K1/K2 (single block) ----
    {
        float k1 = 0.f, k2 = 0.f;
        if (tid < C_) {
            float gw_ = g2[tid] * lw[tid];
            gwl[tid] = gw_;
            k1 = gw_;
            k2 = be2[tid] * lw[tid];
        }
#pragma unroll
        for (int m = 32; m; m >>= 1) {
            k1 += __shfl_xor(k1, m, 64);
            k2 += __shfl_xor(k2, m, 64);
        }
        int wv = tid >> 6;
        if ((tid & 63) == 0 && wv < 8) { rk[wv][0] = k1; rk[wv][1] = k2; }
        __syncthreads();
        if (tid == 0) {
            float a1 = 0.f, a2 = 0.f;
#pragma unroll
            for (int i = 0; i < 8; i++) { a1 += rk[i][0]; a2 += rk[i][1]; }
            k12[0] = a1; k12[1] = a2;
        }
    }
}

// ---------------------------------------------------------------------------
// Flatmm implicit-GEMM conv: BM=128 x BN=256 block, 4 waves, wave tile
// 128M x 64N (8x4 frags of 16x16x32).  A via LDS (16KB, granule-swizzled,
// global_load_lds) -- only 4 staging loads/wave/iter -> short barrier drain.
// B read DIRECTLY from L2 as coalesced 1KB fragment loads (B2 layout, no
// LDS, each B col read by exactly one wave).  2 blocks/CU (16KB LDS,
// ~210 VGPR): cross-block overlap hides the A-drain (R7 mechanism).
// EPI=0: Y = relu(A@B^T + bias) -> yws.   Dead block iff t0 > tlen[b].
// EPI=1: per-row partials (S,Q,U=sum v*gwl) over 256 cols -> stats[m][nblk].
//        Dead block iff t0 >= tlen[b].
template<int EPI>
__global__ __launch_bounds__(256, 2) void gemm_k(const f16* __restrict__ A,
                                                 const f16* __restrict__ B2,
                                                 const float* __restrict__ bias,
                                                 f16* __restrict__ Y,
                                                 const float* __restrict__ gwl,
                                                 float4* __restrict__ stats,
                                                 const int* __restrict__ tlen) {
    __shared__ f16 As[128 * 64];   // 16 KB, A only
    const int m0 = blockIdx.x * 128;
    {
        const int bb = m0 >> 10, t0 = m0 & 1023;
        const int L = tlen[bb];
        if (EPI == 0 ? (t0 > L) : (t0 >= L)) return;   // block-uniform
    }
    const int tid = threadIdx.x;
    const int lane = tid & 63;
    const int w = tid >> 6;        // 0..3 (N-split: 4 x 64 cols)
    const int n0 = blockIdx.y * 256;
    const int arow0 = (m0 >> 10) * TP_ + (m0 & 1023);
    const int nt0 = (n0 >> 4) + w * 4;     // wave's first 16-col tile

    f32x4 acc[8][4];
#pragma unroll
    for (int i = 0; i < 8; i++)
#pragma unroll
        for (int j = 0; j < 4; j++) acc[i][j] = (f32x4){0.f, 0.f, 0.f, 0.f};

    const int lrow = lane >> 3;                  // 0..7
    const int gran = (lane & 7) ^ lrow;          // swizzled source granule
    const f16* aB = A + (size_t)(arow0 + lrow) * C_ + gran * 8;

    for (int kt = 0; kt < NKT; ++kt) {
        const int kk = kt * 64;
        __syncthreads();                         // prev iter's As reads done
#pragma unroll
        for (int i = 0; i < 4; i++) {            // A: 16 wave-loads / 4 waves
            const int rb = (w + i * 4) * 8;
            __builtin_amdgcn_global_load_lds(AS1C(aB + (size_t)rb * C_ + kk),
                                             AS3(&As[rb * 64]), 16, 0, 0);
        }
        __syncthreads();                         // drain 4 A loads (short)

        // B fragments: 8 coalesced 1KB loads from L2 (both k-slices)
        f16x8 bf0[4], bf1[4];
#pragma unroll
        for (int ni = 0; ni < 4; ni++) {
            const size_t base = ((size_t)((kt * 32 + nt0 + ni) * 2) << 9) + lane * 8;
            bf0[ni] = *(const f16x8*)&B2[base];
            bf1[ni] = *(const f16x8*)&B2[base + 512];
        }
#pragma unroll
        for (int ks = 0; ks < 2; ks++) {
            const int sl = ((ks << 2) + (lane >> 4)) ^ (lane & 7);
            f16x8 af[8];
#pragma unroll
            for (int mi = 0; mi < 8; mi++)
                af[mi] = *(const f16x8*)&As[(mi * 16 + (lane & 15)) * 64 + sl * 8];
#pragma unroll
            for (int mi = 0; mi < 8; mi++)
#pragma unroll
                for (int ni = 0; ni < 4; ni++)
                    acc[mi][ni] = __builtin_amdgcn_mfma_f32_16x16x32_f16(
                        af[mi], ks ? bf1[ni] : bf0[ni], acc[mi][ni], 0, 0, 0);
        }
    }

    const int col = lane & 15;
    const int row4 = (lane >> 4) * 4;

    if (EPI == 0) {
        // bias + relu -> Y (f16)
#pragma unroll
        for (int ni = 0; ni < 4; ni++) {
            int n = n0 + w * 64 + ni * 16 + col;
            float bn = bias[n];
#pragma unroll
            for (int mi = 0; mi < 8; mi++) {
#pragma unroll
                for (int r = 0; r < 4; r++) {
                    int m = m0 + mi * 16 + row4 + r;
                    float v = acc[mi][ni][r] + bn;
                    Y[(size_t)m * C_ + n] = (f16)(v > 0.f ? v : 0.f);
                }
            }
        }
    } else {
        // partial stats over this block's 256 cols
        float bn[4], gw[4];
#pragma unroll
        for (int ni = 0; ni < 4; ni++) {
            int n = n0 + w * 64 + ni * 16 + col;
            bn[ni] = bias[n];
            gw[ni] = gwl[n];
        }
        float s_[8][4], q_[8][4], u_[8][4];
#pragma unroll
        for (int mi = 0; mi < 8; mi++)
#pragma unroll
            for (int r = 0; r < 4; r++) { s_[mi][r] = 0.f; q_[mi][r] = 0.f; u_[mi][r] = 0.f; }
#pragma unroll
        for (int mi = 0; mi < 8; mi++)
#pragma unroll
            for (int ni = 0; ni < 4; ni++)
#pragma unroll
                for (int r = 0; r < 4; r++) {
                    float v = acc[mi][ni][r] + bn[ni];
                    v = v > 0.f ? v : 0.f;
                    s_[mi][r] += v;
                    q_[mi][r] += v * v;
                    u_[mi][r] += v * gw[ni];
                }
        // reduce across the 16 col-lanes (rows live at fixed lane>>4)
#pragma unroll
        for (int m = 8; m; m >>= 1)
#pragma unroll
            for (int mi = 0; mi < 8; mi++)
#pragma unroll
                for (int r = 0; r < 4; r++) {
                    s_[mi][r] += __shfl_xor(s_[mi][r], m, 64);
                    q_[mi][r] += __shfl_xor(q_[mi][r], m, 64);
                    u_[mi][r] += __shfl_xor(u_[mi][r], m, 64);
                }
        // cross-wave combine: 4 waves hold disjoint 64-col ranges, same rows
        __syncthreads();                       // main-loop LDS reads done
        float* red = (float*)As;               // [4][128][3] = 6 KB
        if (col == 0) {
#pragma unroll
            for (int mi = 0; mi < 8; mi++)
#pragma unroll
                for (int r = 0; r < 4; r++) {
                    int row = mi * 16 + row4 + r;        // 0..127
                    int idx = (w * 128 + row) * 3;
                    red[idx]     = s_[mi][r];
                    red[idx + 1] = q_[mi][r];
                    red[idx + 2] = u_[mi][r];
                }
        }
        __syncthreads();
        if (tid < 128) {
            float S = 0.f, Q = 0.f, U = 0.f;
#pragma unroll
            for (int wv = 0; wv < 4; wv++) {
                int idx = (wv * 128 + tid) * 3;
                S += red[idx]; Q += red[idx + 1]; U += red[idx + 2];
            }
            stats[(size_t)(m0 + tid) * 2 + blockIdx.y] = (float4){S, Q, U, 0.f};
        }
    }
}

// ---------------------------------------------------------------------------
// LayerNorm over C=512 (input f16), wave per row, write fp16 into h1pad.
// Skips rows t > tlen[b] (outputs never read by live gemm2 rows).
__global__ __launch_bounds__(256) void ln_kernel(const f16* __restrict__ Y,
                                                 const float* __restrict__ g,
                                                 const float* __restrict__ be,
                                                 f16* __restrict__ hpad,
                                                 const int* __restrict__ tlen) {
    int row = blockIdx.x * 4 + (threadIdx.x >> 6);
    int lane = threadIdx.x & 63;
    int b = row >> 10, t = row & 1023;
    if (t > tlen[b]) return;                 // wave-uniform
    f16x8 yv = *(const f16x8*)(Y + (size_t)row * C_ + lane * 8);
    float v[8];
#pragma unroll
    for (int i = 0; i < 8; i++) v[i] = (float)yv[i];
    float s = 0.f, q = 0.f;
#pragma unroll
    for (int i = 0; i < 8; i++) { s += v[i]; q += v[i] * v[i]; }
#pragma unroll
    for (int m = 32; m; m >>= 1) { s += __shfl_xor(s, m, 64); q += __shfl_xor(q, m, 64); }
    float mu = s * (1.f / 512.f);
    float x = q * (1.f / 512.f) - mu * mu + 1e-5f;
    float rs = rsqrtf(x);
    rs = rs * (1.5f - 0.5f * x * rs * rs);   // Newton refine
    const float4 g0 = ((const float4*)g)[lane * 2], g1 = ((const float4*)g)[lane * 2 + 1];
    const float4 e0 = ((const float4*)be)[lane * 2], e1 = ((const float4*)be)[lane * 2 + 1];
    f16x8 h;
    h[0] = (f16)((v[0] - mu) * rs * g0.x + e0.x);
    h[1] = (f16)((v[1] - mu) * rs * g0.y + e0.y);
    h[2] = (f16)((v[2] - mu) * rs * g0.z + e0.z);
    h[3] = (f16)((v[3] - mu) * rs * g0.w + e0.w);
    h[4] = (f16)((v[4] - mu) * rs * g1.x + e1.x);
    h[5] = (f16)((v[5] - mu) * rs * g1.y + e1.y);
    h[6] = (f16)((v[6] - mu) * rs * g1.z + e1.z);
    h[7] = (f16)((v[7] - mu) * rs * g1.w + e1.w);
    *(f16x8*)(hpad + ((size_t)(b * TP_ + t + 1)) * C_ + lane * 8) = h;
}

// ---------------------------------------------------------------------------
// merged: [0,32768) regulate gather; [32768,32896) finalize pred.
__global__ __launch_bounds__(256) void gather_fin(const float* __restrict__ batch,
                                                  const int* __restrict__ idxarr,
                                                  const int* __restrict__ total,
                                                  float* __restrict__ out,
                                                  const float4* __restrict__ stats,
                                                  const float* __restrict__ k12,
                                                  const float* __restrict__ lb,
                                                  const int* __restrict__ tlen,
                                                  float* __restrict__ pred) {
    if (blockIdx.x < 32768) {
        int gw = blockIdx.x * 4 + (threadIdx.x >> 6);  // 0 .. B_*LMAX_-1
        int lane = threadIdx.x & 63;
        int b = gw >> 12;
        int l = gw & (LMAX_ - 1);
        int tot = total[b];
        float4* dst = (float4*)(out + ((size_t)b * LMAX_ + l) * C_);
        if (l < tot) {
            int idx = idxarr[gw];
            const float4* src = (const float4*)(batch + ((size_t)b * T_ + idx) * C_);
            dst[lane] = src[lane];
            dst[lane + 64] = src[lane + 64];
        } else {
            float4 z = {0.f, 0.f, 0.f, 0.f};
            dst[lane] = z;
            dst[lane + 64] = z;
        }
    } else {
        int m = (blockIdx.x - 32768) * 256 + threadIdx.x;   // 0..32767
        float4 a = stats[(size_t)m * 2];
        float4 b = stats[(size_t)m * 2 + 1];
        float S = a.x + b.x, Q = a.y + b.y, U = a.z + b.z;
        float mu = S * (1.f / 512.f);
        float x = Q * (1.f / 512.f) - mu * mu + 1e-5f;
        float rs = rsqrtf(x);
        rs = rs * (1.5f - 0.5f * x * rs * rs);
        float p = rs * (U - mu * k12[0]) + k12[1] + lb[0];
        int bb = m >> 10, t = m & 1023;
        pred[m] = (t < tlen[bb]) ? p : 0.f;
    }
}

// ---------------------------------------------------------------------------
extern "C" void kernel_launch(void* const* d_in, const int* in_sizes, int n_in,
                              void* d_out, int out_size, void* d_ws, size_t ws_size,
                              hipStream_t stream) {
    const float* batch = (const float*)d_in[0];
    const int* tlen    = (const int*)d_in[1];
    const int* durs    = (const int*)d_in[3];
    const float* w1  = (const float*)d_in[4];
    const float* b1  = (const float*)d_in[5];
    const float* g1  = (const float*)d_in[6];
    const float* be1 = (const float*)d_in[7];
    const float* w2  = (const float*)d_in[8];
    const float* b2  = (const float*)d_in[9];
    const float* g2  = (const float*)d_in[10];
    const float* be2 = (const float*)d_in[11];
    const float* lw  = (const float*)d_in[12];
    const float* lb  = (const float*)d_in[13];

    float* out      = (float*)d_out;
    float* mel_out  = out + (size_t)B_ * LMAX_ * C_;
    float* pred_out = mel_out + B_;

    char* ws    = (char*)d_ws;
    f16* xpad   = (f16*)(ws + XPAD_OFF);
    f16* h1pad  = (f16*)(ws + H1PAD_OFF);
    f16* w1t    = (f16*)(ws + W1T_OFF);
    f16* w2t    = (f16*)(ws + W2T_OFF);
    f16* yws    = (f16*)(ws + YWS_OFF);
    int* tot    = (int*)(ws + TOT_OFF);
    int* idxarr = (int*)(ws + IDX_OFF);
    float* gwl  = (float*)(ws + GWL_OFF);
    float* k12  = (float*)(ws + K12_OFF);
    float4* st2 = (float4*)(ws + STAT2_OFF);

    fused_prep<<<PP_BLOCKS + PW_BLOCKS + SCAN_BLOCKS + 1, 1024, 0, stream>>>(
        batch, xpad, h1pad, tlen, w1, w2, w1t, w2t,
        g2, be2, lw, gwl, k12, durs, idxarr, tot, mel_out);
    gemm_k<0><<<dim3(256, 2), 256, 0, stream>>>(xpad, w1t, b1, yws,
                                                nullptr, nullptr, tlen);
    ln_kernel<<<8192, 256, 0, stream>>>(yws, g1, be1, h1pad, tlen);
    gemm_k<1><<<dim3(256, 2), 256, 0, stream>>>(h1pad, w2t, b2, nullptr,
                                                gwl, st2, tlen);
    gather_fin<<<32768 + 128, 256, 0, stream>>>(batch, idxarr, tot, out,
                                                st2, k12, lb, tlen, pred_out);
}

// Round 9
// 456.884 us; speedup vs baseline: 1.0441x; 1.0228x over previous
//
#include <hip/hip_runtime.h>
#include <hip/hip_bf16.h>
#include <stdint.h>

// R7 466.7 unfused. R8/R10/R11 ~500: 1-block/CU fused geometries fail.
// R12 462.1: gemm2 -> partial stats. R13 450.2 BEST: fused_prep + dead-work
//   skips. R14 477: hetero merge throttled gather occupancy. R15 467:
//   flatmm B-from-L2 exposed B load latency on the MFMA critical path.
// R16: R13 + gemm k-loop rebuilt as triple-buffered BK=32 counted-vmcnt
//   pipeline AT 2 blocks/CU (untested combo: R10/R11 pipelines were
//   1 block/CU; R13 has the 2-block overlap but drains vmcnt(0) 24x).
//   72KB LDS (3x(8+16)KB) -> 2 blocks/CU preserved; vmcnt(12) steady state
//   (6 loads/wave/tile, 2 tiles in flight).  Swizzle/layout = R11's
//   refcheck-passed BK=32 scheme.  Plus bijective XCD-chunk swizzle
//   (512 = 8*64): each XCD owns 32 consecutive m-blocks x both panels ->
//   A tiles + both B panels stay L2-resident per XCD.

typedef _Float16 f16;
typedef _Float16 f16x8 __attribute__((ext_vector_type(8)));
typedef float f32x4 __attribute__((ext_vector_type(4)));

#define B_    32
#define T_    1024
#define TP_   1026
#define C_    512
#define LMAX_ 4096
#define KDIM  1536
#define NK    48         // KDIM/32

// workspace byte offsets (all 256-aligned)
#define XPAD_OFF   0u
#define H1PAD_OFF  33619968u     // 32*1026*512*2
#define W1T_OFF    67239936u
#define W2T_OFF    68812800u
#define YWS_OFF    70385664u     // f16, 32 MB
#define TOT_OFF    137494528u
#define IDX_OFF    137495040u    // + 32*4096*4 = ends 138019328
#define GWL_OFF    138019328u    // 512 f32
#define K12_OFF    138021376u    // 2 f32 (256-pad)
#define STAT2_OFF  138021888u    // 32768*2 float4 = 1 MB

#define AS1C(p) ((const __attribute__((address_space(1))) void*)(p))
#define AS3(p)  ((__attribute__((address_space(3))) void*)(p))

// fused_prep grid partition (1024 threads/block)
#define PP_BLOCKS   2052         // prep_pad: 32832 rows / 16 per block
#define PW_BLOCKS   256          // prep_w: 1024 units / 4 per block
#define SCAN_BLOCKS 32

// ---------------------------------------------------------------------------
// One dispatch running four independent prep stages concurrently (R13 version).
__global__ __launch_bounds__(1024) void fused_prep(
        const float* __restrict__ batch, f16* __restrict__ xpad,
        f16* __restrict__ h1pad, const int* __restrict__ tlen,
        const float* __restrict__ w1, const float* __restrict__ w2,
        f16* __restrict__ w1t, f16* __restrict__ w2t,
        const float* __restrict__ g2, const float* __restrict__ be2,
        const float* __restrict__ lw, float* __restrict__ gwl,
        float* __restrict__ k12,
        const int* __restrict__ dur, int* __restrict__ idxarr,
        int* __restrict__ total, float* __restrict__ mel_out) {
    __shared__ int sd[1024];
    __shared__ int sv[1024];
    __shared__ float rk[8][2];
    const int bid = blockIdx.x;
    const int tid = threadIdx.x;

    if (bid < PP_BLOCKS) {                       // ---- prep_pad ----
        int row = bid * 16 + (tid >> 6);         // 0 .. 32831
        int lane = tid & 63;
        int b = row / TP_, tt = row % TP_;
        size_t dsto = (size_t)row * C_ + lane * 8;
        if (tt == 0 || tt == TP_ - 1) {
            f16x8 z = {};
            *(f16x8*)(xpad + dsto) = z;
            *(f16x8*)(h1pad + dsto) = z;
        } else if (tt <= tlen[b] + 130) {        // dead rows stay poisoned
            const float* src = batch + ((size_t)(b * T_ + tt - 1)) * C_ + lane * 8;
            float4 v0 = ((const float4*)src)[0];
            float4 v1 = ((const float4*)src)[1];
            f16x8 h;
            h[0] = (f16)v0.x; h[1] = (f16)v0.y; h[2] = (f16)v0.z; h[3] = (f16)v0.w;
            h[4] = (f16)v1.x; h[5] = (f16)v1.y; h[6] = (f16)v1.z; h[7] = (f16)v1.w;
            *(f16x8*)(xpad + dsto) = h;
        }
        return;
    }
    if (bid < PP_BLOCKS + PW_BLOCKS) {           // ---- prep_w ----
        int unit = (bid - PP_BLOCKS) * 4 + (tid >> 8);  // 0..1023
        int o = unit & 511;
        const float* w = (unit >> 9) ? w2 : w1;
        f16* wt = (unit >> 9) ? w2t : w1t;
        int tl = tid & 255;
        for (int j = tl; j < KDIM; j += 256) {
            int tap = j >> 9, i = j & 511;
            wt[(size_t)o * KDIM + j] = (f16)w[(size_t)o * KDIM + i * 3 + tap];
        }
        return;
    }
    if (bid < PP_BLOCKS + PW_BLOCKS + SCAN_BLOCKS) {   // ---- scan ----
        int b = bid - (PP_BLOCKS + PW_BLOCKS);
        int t = tid;
        int L = tlen[b];
        int valid = (t < L) ? 1 : 0;
        int d = valid ? dur[b * T_ + t] : 0;
        sd[t] = d; sv[t] = valid;
        __syncthreads();
        for (int off = 1; off < 1024; off <<= 1) {
            int x = 0, y = 0;
            if (t >= off) { x = sd[t - off]; y = sv[t - off]; }
            __syncthreads();
            sd[t] += x; sv[t] += y;
            __syncthreads();
        }
        int totd = sd[1023];
        int cur  = (totd == 0) ? sv[t] : sd[t];
        int prev = (t == 0) ? 0 : ((totd == 0) ? sv[t - 1] : sd[t - 1]);
        for (int f = prev; f < cur; f++) idxarr[b * LMAX_ + f] = t;
        if (t == 1023) {
            int tt = (totd == 0) ? sv[1023] : totd;
            total[b] = tt;
            mel_out[b] = (float)tt;
        }
        return;
    }
    // ---- gwl + K1/K2 (single block) ----
    {
        float k1 = 0.f, k2 = 0.f;
        if (tid < C_) {
            float gw_ = g2[tid] * lw[tid];
            gwl[tid] = gw_;
            k1 = gw_;
            k2 = be2[tid] * lw[tid];
        }
#pragma unroll
        for (int m = 32; m; m >>= 1) {
            k1 += __shfl_xor(k1, m, 64);
            k2 += __shfl_xor(k2, m, 64);
        }
        int wv = tid >> 6;
        if ((tid & 63) == 0 && wv < 8) { rk[wv][0] = k1; rk[wv][1] = k2; }
        __syncthreads();
        if (tid == 0) {
            float a1 = 0.f, a2 = 0.f;
#pragma unroll
            for (int i = 0; i < 8; i++) { a1 += rk[i][0]; a2 += rk[i][1]; }
            k12[0] = a1; k12[1] = a2;
        }
    }
}

// ---------------------------------------------------------------------------
// implicit-GEMM conv: BM=128 x BN=256, 4 waves, wave tile 64x128 (4x8 frags
// of 16x16x32).  BK=32 TRIPLE-buffered (72KB LDS -> 2 blocks/CU) with
// counted-vmcnt pipeline: per iter STAGE(t+2) -> vmcnt(12) -> barrier ->
// 12 ds_read_b128 + 32 MFMA -> barrier.  6 loads/wave/tile, 2 tiles in
// flight, vmcnt never 0 in steady state.  Swizzle (R11-verified): LDS row r
// slot s holds global granule s^(r&3)^((r>>2)&3); pre-swizzled source +
// swizzled read, linear dest.  XCD-chunk block swizzle (bijective 8x64).
// EPI=0: Y = relu(A@Bw^T+bias).  EPI=1: per-row partials (S,Q,U) -> stats.
template<int EPI>
__global__ __launch_bounds__(256, 2) void gemm_k(const f16* __restrict__ A,
                                                 const f16* __restrict__ Bw,
                                                 const float* __restrict__ bias,
                                                 f16* __restrict__ Y,
                                                 const float* __restrict__ gwl,
                                                 float4* __restrict__ stats,
                                                 const int* __restrict__ tlen) {
    __shared__ f16 lds_[36864];          // 72 KB: A0|A1|A2|B0|B1|B2
    f16* const A0 = lds_;                // 128*32 = 4096 f16 (8 KB) each
    f16* const A1 = lds_ + 4096;
    f16* const A2 = lds_ + 8192;
    f16* const B0 = lds_ + 12288;        // 256*32 = 8192 f16 (16 KB) each
    f16* const B1 = lds_ + 20480;
    f16* const B2 = lds_ + 28672;

    // XCD-chunk swizzle: consecutive-on-XCD bids get contiguous (m,panel)
    const int bid = blockIdx.x;                  // 0..511
    const int wg  = (bid & 7) * 64 + (bid >> 3); // bijective (512 = 8*64)
    const int m0  = (wg >> 1) * 128;
    const int n0  = (wg & 1) * 256;
    {
        const int bb = m0 >> 10, t0 = m0 & 1023;
        const int L = tlen[bb];
        if (EPI == 0 ? (t0 > L) : (t0 >= L)) return;   // block-uniform
    }
    const int tid = threadIdx.x;
    const int lane = tid & 63;
    const int w = tid >> 6;              // 0..3
    const int wm = (w & 1) * 64;
    const int wn = (w >> 1) * 128;
    const int arow0 = (m0 >> 10) * TP_ + (m0 & 1023);

    f32x4 acc[4][8];
#pragma unroll
    for (int i = 0; i < 4; i++)
#pragma unroll
        for (int j = 0; j < 8; j++) acc[i][j] = (f32x4){0.f, 0.f, 0.f, 0.f};

    // swizzle permutation (serves staging-source granule and read slot)
    const int perm = (lane & 3) ^ ((lane >> 2) & 3) ^ ((lane >> 4) & 3);
    const int rdo = perm * 8;            // read byte-slot offset (f16 units)
    // staging source bases: lane covers row (base16 + lane>>2), granule perm
    const f16* aB = A + (size_t)(arow0 + (lane >> 2)) * C_ + perm * 8;
    const f16* bB = Bw + (size_t)(n0 + (lane >> 2)) * KDIM + perm * 8;

#define STAGE(Ad, Bd, kofs) do {                                              \
        _Pragma("unroll")                                                     \
        for (int i_ = 0; i_ < 2; i_++) {                                      \
            const int rb = (w + i_ * 4) * 16;                                 \
            __builtin_amdgcn_global_load_lds(                                 \
                AS1C(aB + (size_t)rb * C_ + (kofs)),                          \
                AS3((Ad) + rb * 32), 16, 0, 0);                               \
        }                                                                     \
        _Pragma("unroll")                                                     \
        for (int j_ = 0; j_ < 4; j_++) {                                      \
            const int rb = (w + j_ * 4) * 16;                                 \
            __builtin_amdgcn_global_load_lds(                                 \
                AS1C(bB + (size_t)rb * KDIM + (kofs)),                        \
                AS3((Bd) + rb * 32), 16, 0, 0);                               \
        }                                                                     \
    } while (0)

#define COMPUTE(Ac, Bc) do {                                                  \
        f16x8 af[4], bf[8];                                                   \
        _Pragma("unroll")                                                     \
        for (int mi = 0; mi < 4; mi++)                                        \
            af[mi] = *(const f16x8*)&(Ac)[(wm + mi * 16 + (lane & 15)) * 32 + rdo]; \
        _Pragma("unroll")                                                     \
        for (int ni = 0; ni < 8; ni++)                                        \
            bf[ni] = *(const f16x8*)&(Bc)[(wn + ni * 16 + (lane & 15)) * 32 + rdo]; \
        _Pragma("unroll")                                                     \
        for (int mi = 0; mi < 4; mi++)                                        \
            _Pragma("unroll")                                                 \
            for (int ni = 0; ni < 8; ni++)                                    \
                acc[mi][ni] = __builtin_amdgcn_mfma_f32_16x16x32_f16(         \
                    af[mi], bf[ni], acc[mi][ni], 0, 0, 0);                    \
    } while (0)

#define ITER(Ac, Bc, tval, DO_STAGE, An2, Bn2, VMSTR) do {                    \
        if (DO_STAGE) STAGE(An2, Bn2, ((tval) + 2) * 32);                     \
        asm volatile("s_waitcnt " VMSTR ::: "memory");                        \
        __builtin_amdgcn_s_barrier();                                         \
        __builtin_amdgcn_sched_barrier(0);                                    \
        COMPUTE(Ac, Bc);                                                      \
        __builtin_amdgcn_sched_barrier(0);                                    \
        __builtin_amdgcn_s_barrier();                                         \
    } while (0)

    STAGE(A0, B0, 0);                    // prologue: tiles 0,1 in flight
    STAGE(A1, B1, 32);

    for (int tt = 0; tt < NK - 3; tt += 3) {     // tt = 0,3,...,42
        ITER(A0, B0, tt,     1, A2, B2, "vmcnt(12)");
        ITER(A1, B1, tt + 1, 1, A0, B0, "vmcnt(12)");
        ITER(A2, B2, tt + 2, 1, A1, B1, "vmcnt(12)");
    }
    ITER(A0, B0, NK - 3, 1, A2, B2, "vmcnt(12)");   // t=45, stages tile 47
    ITER(A1, B1, NK - 2, 0, A0, B0, "vmcnt(6)");    // t=46
    ITER(A2, B2, NK - 1, 0, A1, B1, "vmcnt(0)");    // t=47

#undef ITER
#undef COMPUTE
#undef STAGE

    const int col = lane & 15;
    const int row4 = (lane >> 4) * 4;

    if (EPI == 0) {
        // bias + relu -> Y (f16)
#pragma unroll
        for (int ni = 0; ni < 8; ni++) {
            int n = n0 + wn + ni * 16 + col;
            float bn = bias[n];
#pragma unroll
            for (int mi = 0; mi < 4; mi++) {
#pragma unroll
                for (int r = 0; r < 4; r++) {
                    int m = m0 + wm + mi * 16 + row4 + r;
                    float v = acc[mi][ni][r] + bn;
                    Y[(size_t)m * C_ + n] = (f16)(v > 0.f ? v : 0.f);
                }
            }
        }
    } else {
        // partial stats over this block's 256 cols
        float bn[8], gw[8];
#pragma unroll
        for (int ni = 0; ni < 8; ni++) {
            int n = n0 + wn + ni * 16 + col;
            bn[ni] = bias[n];
            gw[ni] = gwl[n];
        }
        float s_[4][4], q_[4][4], u_[4][4];
#pragma unroll
        for (int mi = 0; mi < 4; mi++)
#pragma unroll
            for (int r = 0; r < 4; r++) { s_[mi][r] = 0.f; q_[mi][r] = 0.f; u_[mi][r] = 0.f; }
#pragma unroll
        for (int mi = 0; mi < 4; mi++)
#pragma unroll
            for (int ni = 0; ni < 8; ni++)
#pragma unroll
                for (int r = 0; r < 4; r++) {
                    float v = acc[mi][ni][r] + bn[ni];
                    v = v > 0.f ? v : 0.f;
                    s_[mi][r] += v;
                    q_[mi][r] += v * v;
                    u_[mi][r] += v * gw[ni];
                }
#pragma unroll
        for (int m = 8; m; m >>= 1)
#pragma unroll
            for (int mi = 0; mi < 4; mi++)
#pragma unroll
                for (int r = 0; r < 4; r++) {
                    s_[mi][r] += __shfl_xor(s_[mi][r], m, 64);
                    q_[mi][r] += __shfl_xor(q_[mi][r], m, 64);
                    u_[mi][r] += __shfl_xor(u_[mi][r], m, 64);
                }
        // cross-wave combine (waves w and w+2 share rows, different cols)
        __syncthreads();                       // main-loop LDS reads done
        float* red = (float*)A0;               // [2][128][3] = 3 KB
        if (col == 0) {
#pragma unroll
            for (int mi = 0; mi < 4; mi++)
#pragma unroll
                for (int r = 0; r < 4; r++) {
                    int row = wm + mi * 16 + row4 + r;   // 0..127
                    int idx = ((w >> 1) * 128 + row) * 3;
                    red[idx]     = s_[mi][r];
                    red[idx + 1] = q_[mi][r];
                    red[idx + 2] = u_[mi][r];
                }
        }
        __syncthreads();
        if (tid < 128) {
            float S = red[tid * 3]     + red[(128 + tid) * 3];
            float Q = red[tid * 3 + 1] + red[(128 + tid) * 3 + 1];
            float U = red[tid * 3 + 2] + red[(128 + tid) * 3 + 2];
            stats[(size_t)(m0 + tid) * 2 + (wg & 1)] = (float4){S, Q, U, 0.f};
        }
    }
}

// ---------------------------------------------------------------------------
// LayerNorm over C=512 (input f16), wave per row, write fp16 into h1pad.
// Skips rows t > tlen[b] (outputs never read by live gemm2 rows).
__global__ __launch_bounds__(256) void ln_kernel(const f16* __restrict__ Y,
                                                 const float* __restrict__ g,
                                                 const float* __restrict__ be,
                                                 f16* __restrict__ hpad,
                                                 const int* __restrict__ tlen) {
    int row = blockIdx.x * 4 + (threadIdx.x >> 6);
    int lane = threadIdx.x & 63;
    int b = row >> 10, t = row & 1023;
    if (t > tlen[b]) return;                 // wave-uniform
    f16x8 yv = *(const f16x8*)(Y + (size_t)row * C_ + lane * 8);
    float v[8];
#pragma unroll
    for (int i = 0; i < 8; i++) v[i] = (float)yv[i];
    float s = 0.f, q = 0.f;
#pragma unroll
    for (int i = 0; i < 8; i++) { s += v[i]; q += v[i] * v[i]; }
#pragma unroll
    for (int m = 32; m; m >>= 1) { s += __shfl_xor(s, m, 64); q += __shfl_xor(q, m, 64); }
    float mu = s * (1.f / 512.f);
    float x = q * (1.f / 512.f) - mu * mu + 1e-5f;
    float rs = rsqrtf(x);
    rs = rs * (1.5f - 0.5f * x * rs * rs);   // Newton refine
    const float4 g0 = ((const float4*)g)[lane * 2], g1 = ((const float4*)g)[lane * 2 + 1];
    const float4 e0 = ((const float4*)be)[lane * 2], e1 = ((const float4*)be)[lane * 2 + 1];
    f16x8 h;
    h[0] = (f16)((v[0] - mu) * rs * g0.x + e0.x);
    h[1] = (f16)((v[1] - mu) * rs * g0.y + e0.y);
    h[2] = (f16)((v[2] - mu) * rs * g0.z + e0.z);
    h[3] = (f16)((v[3] - mu) * rs * g0.w + e0.w);
    h[4] = (f16)((v[4] - mu) * rs * g1.x + e1.x);
    h[5] = (f16)((v[5] - mu) * rs * g1.y + e1.y);
    h[6] = (f16)((v[6] - mu) * rs * g1.z + e1.z);
    h[7] = (f16)((v[7] - mu) * rs * g1.w + e1.w);
    *(f16x8*)(hpad + ((size_t)(b * TP_ + t + 1)) * C_ + lane * 8) = h;
}

// ---------------------------------------------------------------------------
// merged: [0,32768) regulate gather; [32768,32896) finalize pred.
__global__ __launch_bounds__(256) void gather_fin(const float* __restrict__ batch,
                                                  const int* __restrict__ idxarr,
                                                  const int* __restrict__ total,
                                                  float* __restrict__ out,
                                                  const float4* __restrict__ stats,
                                                  const float* __restrict__ k12,
                                                  const float* __restrict__ lb,
                                                  const int* __restrict__ tlen,
                                                  float* __restrict__ pred) {
    if (blockIdx.x < 32768) {
        int gw = blockIdx.x * 4 + (threadIdx.x >> 6);  // 0 .. B_*LMAX_-1
        int lane = threadIdx.x & 63;
        int b = gw >> 12;
        int l = gw & (LMAX_ - 1);
        int tot = total[b];
        float4* dst = (float4*)(out + ((size_t)b * LMAX_ + l) * C_);
        if (l < tot) {
            int idx = idxarr[gw];
            const float4* src = (const float4*)(batch + ((size_t)b * T_ + idx) * C_);
            dst[lane] = src[lane];
            dst[lane + 64] = src[lane + 64];
        } else {
            float4 z = {0.f, 0.f, 0.f, 0.f};
            dst[lane] = z;
            dst[lane + 64] = z;
        }
    } else {
        int m = (blockIdx.x - 32768) * 256 + threadIdx.x;   // 0..32767
        float4 a = stats[(size_t)m * 2];
        float4 b = stats[(size_t)m * 2 + 1];
        float S = a.x + b.x, Q = a.y + b.y, U = a.z + b.z;
        float mu = S * (1.f / 512.f);
        float x = Q * (1.f / 512.f) - mu * mu + 1e-5f;
        float rs = rsqrtf(x);
        rs = rs * (1.5f - 0.5f * x * rs * rs);
        float p = rs * (U - mu * k12[0]) + k12[1] + lb[0];
        int bb = m >> 10, t = m & 1023;
        pred[m] = (t < tlen[bb]) ? p : 0.f;
    }
}

// ---------------------------------------------------------------------------
extern "C" void kernel_launch(void* const* d_in, const int* in_sizes, int n_in,
                              void* d_out, int out_size, void* d_ws, size_t ws_size,
                              hipStream_t stream) {
    const float* batch = (const float*)d_in[0];
    const int* tlen    = (const int*)d_in[1];
    const int* durs    = (const int*)d_in[3];
    const float* w1  = (const float*)d_in[4];
    const float* b1  = (const float*)d_in[5];
    const float* g1  = (const float*)d_in[6];
    const float* be1 = (const float*)d_in[7];
    const float* w2  = (const float*)d_in[8];
    const float* b2  = (const float*)d_in[9];
    const float* g2  = (const float*)d_in[10];
    const float* be2 = (const float*)d_in[11];
    const float* lw  = (const float*)d_in[12];
    const float* lb  = (const float*)d_in[13];

    float* out      = (float*)d_out;
    float* mel_out  = out + (size_t)B_ * LMAX_ * C_;
    float* pred_out = mel_out + B_;

    char* ws    = (char*)d_ws;
    f16* xpad   = (f16*)(ws + XPAD_OFF);
    f16* h1pad  = (f16*)(ws + H1PAD_OFF);
    f16* w1t    = (f16*)(ws + W1T_OFF);
    f16* w2t    = (f16*)(ws + W2T_OFF);
    f16* yws    = (f16*)(ws + YWS_OFF);
    int* tot    = (int*)(ws + TOT_OFF);
    int* idxarr = (int*)(ws + IDX_OFF);
    float* gwl  = (float*)(ws + GWL_OFF);
    float* k12  = (float*)(ws + K12_OFF);
    float4* st2 = (float4*)(ws + STAT2_OFF);

    fused_prep<<<PP_BLOCKS + PW_BLOCKS + SCAN_BLOCKS + 1, 1024, 0, stream>>>(
        batch, xpad, h1pad, tlen, w1, w2, w1t, w2t,
        g2, be2, lw, gwl, k12, durs, idxarr, tot, mel_out);
    gemm_k<0><<<512, 256, 0, stream>>>(xpad, w1t, b1, yws,
                                       nullptr, nullptr, tlen);
    ln_kernel<<<8192, 256, 0, stream>>>(yws, g1, be1, h1pad, tlen);
    gemm_k<1><<<512, 256, 0, stream>>>(h1pad, w2t, b2, nullptr,
                                       gwl, st2, tlen);
    gather_fin<<<32768 + 128, 256, 0, stream>>>(batch, idxarr, tot, out,
                                                st2, k12, lb, tlen, pred_out);
}